// Round 3
// baseline (759.171 us; speedup 1.0000x reference)
//
#include <hip/hip_runtime.h>
#include <hip/hip_bf16.h>
#include <math.h>

typedef __attribute__((ext_vector_type(8))) short bf16x8;   // 8 bf16 = 4 VGPRs
typedef __attribute__((ext_vector_type(16))) float f32x16;  // 32x32 mfma acc

#define NUM_PRIORS 11640
#define OUT_CH 25
#define BATCH 32

// ---------------- workspace layout (bytes) ----------------
// WT: bf16 weights in MFMA-frag order [tap][ck][ks][ntile][lane][8]  (unchanged)
#define WT0 0u
#define WT1 1474560u
#define WT2 4423680u
#define WT3 5898240u
#define WT4 6635520u
#define WT5 7372800u
// XA: bf16 A-fragments, zero-padded: [b][C/8][(F+2)^2][8ch] (16B per frag)
#define XA0 8110080u
#define XA1 60538880u
#define XA2 89440256u
#define XA3 94158848u
#define XA4 94961664u
#define XA5 95371264u
// CV: fp32 conv output CONV[s][b][m=y*F+x][n=0..159]
#define CV0 95518720u
#define CV1 125091840u
#define CV2 132485120u
#define CV3 134533120u
#define CV4 135045120u
#define CV5 135229440u
#define WS_TOTAL 135249920u

// ====== prepass 1: OIHW fp32 weights -> bf16 frag order (unchanged) ======
template <int C>
__device__ __forceinline__
void wprep_body(int idx, const float* lw, const float* cw, unsigned short* wt)
{
  if (idx >= 1440 * C) return;
  constexpr int CK = C / 64;
  const int j    = idx & 7;
  const int lane = (idx >> 3) & 63;
  int rest = idx >> 9;
  const int nt  = rest % 5;  rest /= 5;
  const int ks  = rest & 3;  rest >>= 2;
  const int ck  = rest % CK;
  const int tap = rest / CK;
  const int n = nt * 32 + (lane & 31);
  const int c = ck * 64 + ks * 16 + (lane >> 5) * 8 + j;
  float v = 0.f;
  if (n < 24)       v = lw[((size_t)n        * C + c) * 9 + tap];
  else if (n < 150) v = cw[((size_t)(n - 24) * C + c) * 9 + tap];
  __hip_bfloat16 h = __float2bfloat16(v);
  wt[idx] = *(unsigned short*)&h;
}

// ====== prepass 2: NCHW fp32 feats -> padded bf16 A-fragment layout ======
// XA[b][g=c/8][(py)*(F+2)+px][j=0..7], border (py,px==0 or F+1) = 0.
template <int C, int F>
__device__ __forceinline__
void xprep_body(int idx, const float* __restrict__ x, unsigned short* __restrict__ xp)
{
  constexpr int P = F + 2, IMGP = P * P, C8 = C / 8, FF = F * F;
  const int pos = idx % IMGP;
  const int bg  = idx / IMGP;
  const int g   = bg % C8;
  const int b   = bg / C8;
  const int py  = pos / P, px = pos % P;
  uint4 out = {0u, 0u, 0u, 0u};
  if (py >= 1 && py <= F && px >= 1 && px <= F) {
    const float* s = x + (((size_t)(b * C + g * 8) * F + (py - 1)) * F + (px - 1));
    unsigned int u[4];
    #pragma unroll
    for (int k = 0; k < 4; ++k) {
      __hip_bfloat162 h = __float22bfloat162_rn(
          float2{s[(size_t)(2 * k) * FF], s[(size_t)(2 * k + 1) * FF]});
      u[k] = *(unsigned int*)&h;
    }
    out.x = u[0]; out.y = u[1]; out.z = u[2]; out.w = u[3];
  }
  *(uint4*)(xp + (size_t)idx * 8) = out;
}

// block counts (all exact multiples of 256 threads)
#define XB0 12800
#define XB1 7056
#define XB2 1152
#define XB3 196
#define XB4 100
#define XB5 36
#define WB0 2880
#define WB1 5760
#define WB2 2880
#define WB3 1440
#define WB4 1440
#define WB5 1440
#define PB_TOT (XB0+XB1+XB2+XB3+XB4+XB5+WB0+WB1+WB2+WB3+WB4+WB5)

struct PArgs {
  const float* x[6];
  const float* lw[6];
  const float* cw[6];
  unsigned short* xa[6];
  unsigned short* wt[6];
};

__global__ __launch_bounds__(256)
void prep_all(PArgs a)
{
  int blk = blockIdx.x;
  const int t = threadIdx.x;
  if (blk < XB0) { xprep_body<512, 38>(blk * 256 + t, a.x[0], a.xa[0]); return; } blk -= XB0;
  if (blk < XB1) { xprep_body<1024,19>(blk * 256 + t, a.x[1], a.xa[1]); return; } blk -= XB1;
  if (blk < XB2) { xprep_body<512, 10>(blk * 256 + t, a.x[2], a.xa[2]); return; } blk -= XB2;
  if (blk < XB3) { xprep_body<256,  5>(blk * 256 + t, a.x[3], a.xa[3]); return; } blk -= XB3;
  if (blk < XB4) { xprep_body<256,  3>(blk * 256 + t, a.x[4], a.xa[4]); return; } blk -= XB4;
  if (blk < XB5) { xprep_body<256,  1>(blk * 256 + t, a.x[5], a.xa[5]); return; } blk -= XB5;
  if (blk < WB0) { wprep_body<512> (blk * 256 + t, a.lw[0], a.cw[0], a.wt[0]); return; } blk -= WB0;
  if (blk < WB1) { wprep_body<1024>(blk * 256 + t, a.lw[1], a.cw[1], a.wt[1]); return; } blk -= WB1;
  if (blk < WB2) { wprep_body<512> (blk * 256 + t, a.lw[2], a.cw[2], a.wt[2]); return; } blk -= WB2;
  if (blk < WB3) { wprep_body<256> (blk * 256 + t, a.lw[3], a.cw[3], a.wt[3]); return; } blk -= WB3;
  if (blk < WB4) { wprep_body<256> (blk * 256 + t, a.lw[4], a.cw[4], a.wt[4]); return; } blk -= WB4;
                   wprep_body<256> (blk * 256 + t, a.lw[5], a.cw[5], a.wt[5]);
}

// ====== streaming implicit-GEMM conv, n-split across 2 waves/block ========
// Block = 128 threads = 2 waves on one m-tile (64 rows). Wave0: nt 0..2,
// wave1: nt 3..4. Shared A-frag lines hit L1; m=64 keeps 2x B-reuse.
// No LDS, no barriers, no atomics.
template <int C, int F, int NT0, int NTN>
__device__ __forceinline__
void conv_tile(int bid, int lane, const unsigned short* __restrict__ xp,
               const unsigned short* __restrict__ wt, float* __restrict__ cv)
{
  constexpr int FF   = F * F;
  constexpr int NT   = (FF + 63) / 64;
  constexpr int CK   = C / 64;
  constexpr int P    = F + 2;
  constexpr int IMGP = P * P;
  constexpr int C8   = C / 8;

  const int mt = bid % NT;
  const int b  = bid / NT;
  const int m0 = mt * 64;

  const int cm    = lane & 31;
  const int khalf = lane >> 5;

  int mi0 = m0 + cm;      if (mi0 > FF - 1) mi0 = FF - 1;
  int mi1 = m0 + 32 + cm; if (mi1 > FF - 1) mi1 = FF - 1;
  const int ay0 = mi0 / F, ax0 = mi0 - ay0 * F;
  const int ay1 = mi1 / F, ax1 = mi1 - ay1 * F;
  const int ylo = m0 / F;
  const int mtop = (m0 + 63 < FF - 1) ? (m0 + 63) : (FF - 1);
  const int yhi = mtop / F;

  // lane-base into XA for this (b, khalf): frag addr = xb + (g*IMGP + pos)*8 shorts
  const unsigned short* xb = xp + ((size_t)b * C8 + khalf) * IMGP * 8;
  const int o0 = ((ay0 + 1) * P + ax0 + 1) * 8;
  const int o1 = ((ay1 + 1) * P + ax1 + 1) * 8;

  f32x16 acc[2][NTN];
  #pragma unroll
  for (int mf = 0; mf < 2; ++mf)
    #pragma unroll
    for (int nt = 0; nt < NTN; ++nt)
      #pragma unroll
      for (int r = 0; r < 16; ++r) acc[mf][nt][r] = 0.f;

  const unsigned short* wl = wt + lane * 8 + NT0 * 512;

  #pragma unroll 1
  for (int ck = 0; ck < CK; ++ck) {
    const unsigned short* xg  = xb + (size_t)ck * 8 * IMGP * 8;   // g = ck*8 + ks*2 + khalf
    const unsigned short* wck = wl + ck * 10240;
    #pragma unroll
    for (int ks = 0; ks < 4; ++ks) {
      const unsigned short* xk = xg + (size_t)(ks * 2) * IMGP * 8;
      #pragma unroll
      for (int tap = 0; tap < 9; ++tap) {
        constexpr int TS = CK * 10240;
        const int dy = tap / 3 - 1, dx = tap % 3 - 1;
        if (ylo + dy >= F || yhi + dy < 0) continue;   // wave-uniform skip
        if (F == 1 && dx != 0) continue;
        const int d = (dy * P + dx) * 8;               // compile-time per tap
        const bf16x8 a0 = *(const bf16x8*)(xk + o0 + d);
        const bf16x8 a1 = *(const bf16x8*)(xk + o1 + d);
        #pragma unroll
        for (int nt = 0; nt < NTN; ++nt) {
          const bf16x8 bf = *(const bf16x8*)(wck + tap * TS + ks * 2560 + nt * 512);
          acc[0][nt] = __builtin_amdgcn_mfma_f32_32x32x16_bf16(a0, bf, acc[0][nt], 0, 0, 0);
          acc[1][nt] = __builtin_amdgcn_mfma_f32_32x32x16_bf16(a1, bf, acc[1][nt], 0, 0, 0);
        }
      }
    }
  }

  // plain coalesced stores (no split-K => no atomics, no memset needed)
  float* cb = cv + (size_t)b * FF * 160;
  #pragma unroll
  for (int mf = 0; mf < 2; ++mf)
    #pragma unroll
    for (int nt = 0; nt < NTN; ++nt) {
      const int n = (NT0 + nt) * 32 + cm;
      #pragma unroll
      for (int r = 0; r < 16; ++r) {
        const int mm = m0 + mf * 32 + (r & 3) + 8 * (r >> 2) + 4 * khalf;
        if (mm < FF) cb[(size_t)mm * 160 + n] = acc[mf][nt][r];
      }
    }
}

template <int C, int F>
__device__ __forceinline__
void conv_block(int bid, int wave, int lane, const unsigned short* __restrict__ xp,
                const unsigned short* __restrict__ wt, float* __restrict__ cv)
{
  if (wave == 0) conv_tile<C, F, 0, 3>(bid, lane, xp, wt, cv);
  else           conv_tile<C, F, 3, 2>(bid, lane, xp, wt, cv);
}

// per-stage block counts: 32 * ceil(FF/64); heavy stage (C=1024) first
#define G1 192
#define G0 736
#define G2 64
#define G3 32
#define G4 32
#define G5 32
#define GB_TOT (G1 + G0 + G2 + G3 + G4 + G5)

__global__ __launch_bounds__(128, 2)
void gemm_all(char* wsb)
{
  int blk = blockIdx.x;
  const int wave = threadIdx.x >> 6;
  const int lane = threadIdx.x & 63;
  if (blk < G1) { conv_block<1024,19>(blk, wave, lane, (const unsigned short*)(wsb + XA1),
                                      (const unsigned short*)(wsb + WT1), (float*)(wsb + CV1)); return; }
  blk -= G1;
  if (blk < G0) { conv_block<512, 38>(blk, wave, lane, (const unsigned short*)(wsb + XA0),
                                      (const unsigned short*)(wsb + WT0), (float*)(wsb + CV0)); return; }
  blk -= G0;
  if (blk < G2) { conv_block<512, 10>(blk, wave, lane, (const unsigned short*)(wsb + XA2),
                                      (const unsigned short*)(wsb + WT2), (float*)(wsb + CV2)); return; }
  blk -= G2;
  if (blk < G3) { conv_block<256,  5>(blk, wave, lane, (const unsigned short*)(wsb + XA3),
                                      (const unsigned short*)(wsb + WT3), (float*)(wsb + CV3)); return; }
  blk -= G3;
  if (blk < G4) { conv_block<256,  3>(blk, wave, lane, (const unsigned short*)(wsb + XA4),
                                      (const unsigned short*)(wsb + WT4), (float*)(wsb + CV4)); return; }
  blk -= G4;
                  conv_block<256,  1>(blk, wave, lane, (const unsigned short*)(wsb + XA5),
                                      (const unsigned short*)(wsb + WT5), (float*)(wsb + CV5));
}

// ================= decode: bias + softmax + prior decode ==================
struct DecArgs {
  const float* lb[6];
  const float* cb[6];
};

template <int F>
__device__ __forceinline__
void dec_one(int local, int b, const float* cvs, const float* lb, const float* cb,
             const float* p4, float* o)
{
  constexpr int FF = F * F;
  const int pos = local / 6;
  const int a   = local - pos * 6;
  const float* strip = cvs + ((size_t)b * FF + pos) * 160;

  float cls[21];
  float mx = -1e30f;
  #pragma unroll
  for (int k = 0; k < 21; ++k) {
    cls[k] = strip[24 + a * 21 + k] + cb[a * 21 + k];
    mx = fmaxf(mx, cls[k]);
  }
  float s = 0.f;
  #pragma unroll
  for (int k = 0; k < 21; ++k) { cls[k] = __expf(cls[k] - mx); s += cls[k]; }
  const float inv = 1.f / s;

  const float l0 = strip[a * 4 + 0] + lb[a * 4 + 0];
  const float l1 = strip[a * 4 + 1] + lb[a * 4 + 1];
  const float l2 = strip[a * 4 + 2] + lb[a * 4 + 2];
  const float l3 = strip[a * 4 + 3] + lb[a * 4 + 3];

  const float px = p4[0], py = p4[1], pw = p4[2], ph = p4[3];
  const float cx = px + l0 * 0.1f * pw;
  const float cy = py + l1 * 0.1f * ph;
  const float w  = pw * __expf(l2 * 0.2f);
  const float h  = ph * __expf(l3 * 0.2f);
  const float minx = cx - 0.5f * w;
  const float miny = cy - 0.5f * h;

  o[0] = minx; o[1] = miny; o[2] = minx + w; o[3] = miny + h;
  #pragma unroll
  for (int k = 0; k < 21; ++k) o[4 + k] = cls[k] * inv;
}

__global__ __launch_bounds__(256)
void decode_k(const char* __restrict__ wsb, DecArgs da,
              const float* __restrict__ priors, float* __restrict__ out)
{
  const int gid = blockIdx.x * 256 + threadIdx.x;
  if (gid >= BATCH * NUM_PRIORS) return;
  const int b  = gid / NUM_PRIORS;
  const int pr = gid - b * NUM_PRIORS;
  float* o = out + (size_t)gid * OUT_CH;
  const float* p4 = priors + (size_t)pr * 4;

  if (pr < 8664)       dec_one<38>(pr,         b, (const float*)(wsb + CV0), da.lb[0], da.cb[0], p4, o);
  else if (pr < 10830) dec_one<19>(pr - 8664,  b, (const float*)(wsb + CV1), da.lb[1], da.cb[1], p4, o);
  else if (pr < 11430) dec_one<10>(pr - 10830, b, (const float*)(wsb + CV2), da.lb[2], da.cb[2], p4, o);
  else if (pr < 11580) dec_one<5> (pr - 11430, b, (const float*)(wsb + CV3), da.lb[3], da.cb[3], p4, o);
  else if (pr < 11634) dec_one<3> (pr - 11580, b, (const float*)(wsb + CV4), da.lb[4], da.cb[4], p4, o);
  else                 dec_one<1> (pr - 11634, b, (const float*)(wsb + CV5), da.lb[5], da.cb[5], p4, o);
}

// ================= fallback (round-1 direct kernel, known-good) ===========
#define TH 4
#define TW 8
#define NPOS 32
#define NUM_OC 160
#define WS_STRIDE 161
#define OS 33
#define CC 8

union SmemFB {
  struct {
    float patch[CC * (TH + 2) * (TW + 2)];
    float w[9 * CC * WS_STRIDE];
  } st;
  float outbuf[NUM_OC * OS];
};

template <int C, int F>
__global__ __launch_bounds__(256)
void ssd_stage(const float* __restrict__ x,
               const float* __restrict__ loc_w, const float* __restrict__ loc_b,
               const float* __restrict__ conf_w, const float* __restrict__ conf_b,
               const float* __restrict__ priors,
               float* __restrict__ out, int stage_off)
{
  constexpr int nx = (F + TW - 1) / TW;
  constexpr int ny = (F + TH - 1) / TH;
  __shared__ SmemFB smem;

  const int bid = blockIdx.x;
  const int b   = bid / (nx * ny);
  const int rem = bid % (nx * ny);
  const int ty  = rem / nx;
  const int tx  = rem % nx;
  const int x0  = tx * TW;
  const int y0  = ty * TH;

  const int t = threadIdx.x;
  const int g = t & 31;
  const int p = t >> 5;

  float acc[5][TH] = {};

  #pragma unroll 1
  for (int c0 = 0; c0 < C; c0 += CC) {
    __syncthreads();
    for (int i = t; i < CC * (TH + 2) * (TW + 2); i += 256) {
      int c  = i / ((TH + 2) * (TW + 2));
      int r  = i - c * ((TH + 2) * (TW + 2));
      int yy = r / (TW + 2);
      int xx = r - yy * (TW + 2);
      int gy = y0 + yy - 1;
      int gx = x0 + xx - 1;
      float v = 0.f;
      if (gy >= 0 && gy < F && gx >= 0 && gx < F)
        v = x[(((size_t)b * C + (c0 + c)) * F + gy) * F + gx];
      smem.st.patch[i] = v;
    }
    for (int i = t; i < NUM_OC * (CC * 9); i += 256) {
      int oc  = i / (CC * 9);
      int j   = i - oc * (CC * 9);
      int c   = j / 9;
      int tap = j - c * 9;
      float v = 0.f;
      if (oc < 24)        v = loc_w [((size_t)oc        * C + (c0 + c)) * 9 + tap];
      else if (oc < 150)  v = conf_w[((size_t)(oc - 24) * C + (c0 + c)) * 9 + tap];
      smem.st.w[(tap * CC + c) * WS_STRIDE + oc] = v;
    }
    __syncthreads();

    for (int tap = 0; tap < 9; ++tap) {
      const int ky = tap / 3;
      const int kx = tap - ky * 3;
      const int xbase = ky * (TW + 2) + kx + p;
      const int wbase = tap * CC * WS_STRIDE + g;
      #pragma unroll
      for (int c = 0; c < CC; ++c) {
        float xv[TH];
        #pragma unroll
        for (int v = 0; v < TH; ++v)
          xv[v] = smem.st.patch[c * ((TH + 2) * (TW + 2)) + v * (TW + 2) + xbase];
        #pragma unroll
        for (int u = 0; u < 5; ++u) {
          float wv = smem.st.w[wbase + c * WS_STRIDE + u * 32];
          #pragma unroll
          for (int v = 0; v < TH; ++v)
            acc[u][v] += wv * xv[v];
        }
      }
    }
  }

  __syncthreads();
  #pragma unroll
  for (int u = 0; u < 5; ++u) {
    int oc = g + 32 * u;
    float bias = 0.f;
    if (oc < 24)       bias = loc_b[oc];
    else if (oc < 150) bias = conf_b[oc - 24];
    #pragma unroll
    for (int v = 0; v < TH; ++v)
      smem.outbuf[oc * OS + v * TW + p] = acc[u][v] + bias;
  }
  __syncthreads();

  if (t < NPOS * 6) {
    int pos = t / 6;
    int a   = t - pos * 6;
    int lx  = pos & 7;
    int ly  = pos >> 3;
    int gx  = x0 + lx;
    int gy  = y0 + ly;
    if (gx < F && gy < F) {
      float cls[21];
      float m = -1e30f;
      #pragma unroll
      for (int k = 0; k < 21; ++k) {
        cls[k] = smem.outbuf[(24 + a * 21 + k) * OS + pos];
        m = fmaxf(m, cls[k]);
      }
      float s = 0.f;
      #pragma unroll
      for (int k = 0; k < 21; ++k) { cls[k] = __expf(cls[k] - m); s += cls[k]; }
      float inv = 1.f / s;

      float l0 = smem.outbuf[(a * 4 + 0) * OS + pos];
      float l1 = smem.outbuf[(a * 4 + 1) * OS + pos];
      float l2 = smem.outbuf[(a * 4 + 2) * OS + pos];
      float l3 = smem.outbuf[(a * 4 + 3) * OS + pos];

      int prior = stage_off + (gy * F + gx) * 6 + a;
      const float* pr = priors + (size_t)prior * 4;
      float px = pr[0], py = pr[1], pw = pr[2], ph = pr[3];
      float cx = px + l0 * 0.1f * pw;
      float cy = py + l1 * 0.1f * ph;
      float w  = pw * __expf(l2 * 0.2f);
      float h  = ph * __expf(l3 * 0.2f);
      float minx = cx - 0.5f * w;
      float miny = cy - 0.5f * h;

      float* o = out + ((size_t)b * NUM_PRIORS + prior) * OUT_CH;
      o[0] = minx;
      o[1] = miny;
      o[2] = minx + w;
      o[3] = miny + h;
      #pragma unroll
      for (int k = 0; k < 21; ++k)
        o[4 + k] = cls[k] * inv;
    }
  }
}

template <int C, int F>
static void launch_stage_fb(void* const* d_in, int base, const float* priors, float* out,
                            int stage_off, hipStream_t stream) {
  constexpr int nx = (F + TW - 1) / TW;
  constexpr int ny = (F + TH - 1) / TH;
  int blocks = BATCH * nx * ny;
  ssd_stage<C, F><<<blocks, 256, 0, stream>>>(
      (const float*)d_in[base + 0], (const float*)d_in[base + 1], (const float*)d_in[base + 2],
      (const float*)d_in[base + 3], (const float*)d_in[base + 4], priors, out, stage_off);
}

// ================= launch =================================================
extern "C" void kernel_launch(void* const* d_in, const int* in_sizes, int n_in,
                              void* d_out, int out_size, void* d_ws, size_t ws_size,
                              hipStream_t stream) {
  (void)in_sizes; (void)n_in; (void)out_size;
  const float* priors = (const float*)d_in[30];
  float* out = (float*)d_out;

  if (ws_size < (size_t)WS_TOTAL) {   // deterministic fallback
    launch_stage_fb<512,  38>(d_in,  0, priors, out,     0, stream);
    launch_stage_fb<1024, 19>(d_in,  5, priors, out,  8664, stream);
    launch_stage_fb<512,  10>(d_in, 10, priors, out, 10830, stream);
    launch_stage_fb<256,   5>(d_in, 15, priors, out, 11430, stream);
    launch_stage_fb<256,   3>(d_in, 20, priors, out, 11580, stream);
    launch_stage_fb<256,   1>(d_in, 25, priors, out, 11634, stream);
    return;
  }

  char* wsb = (char*)d_ws;
  static const unsigned wtoff[6] = {WT0, WT1, WT2, WT3, WT4, WT5};
  static const unsigned xaoff[6] = {XA0, XA1, XA2, XA3, XA4, XA5};

  // fused prepass: weights -> frag order, feats -> padded bf16 frags
  PArgs pa;
  for (int s = 0; s < 6; ++s) {
    pa.x[s]  = (const float*)d_in[5 * s];
    pa.lw[s] = (const float*)d_in[5 * s + 1];
    pa.cw[s] = (const float*)d_in[5 * s + 3];
    pa.xa[s] = (unsigned short*)(wsb + xaoff[s]);
    pa.wt[s] = (unsigned short*)(wsb + wtoff[s]);
  }
  prep_all<<<PB_TOT, 256, 0, stream>>>(pa);

  // streaming conv, 2 waves/block n-split (no LDS / barriers / atomics)
  gemm_all<<<GB_TOT, 128, 0, stream>>>(wsb);

  // epilogue: bias + softmax + decode
  DecArgs da;
  for (int s = 0; s < 6; ++s) {
    da.lb[s] = (const float*)d_in[5 * s + 2];
    da.cb[s] = (const float*)d_in[5 * s + 4];
  }
  decode_k<<<(BATCH * NUM_PRIORS + 255) / 256, 256, 0, stream>>>((const char*)d_ws, da, priors, out);
}

// Round 4
// 490.782 us; speedup vs baseline: 1.5469x; 1.5469x over previous
//
#include <hip/hip_runtime.h>
#include <hip/hip_bf16.h>
#include <math.h>

typedef __attribute__((ext_vector_type(8))) short bf16x8;   // 8 bf16 = 4 VGPRs
typedef __attribute__((ext_vector_type(16))) float f32x16;  // 32x32 mfma acc

#define NUM_PRIORS 11640
#define OUT_CH 25
#define BATCH 32

// ---------------- workspace layout (bytes) ----------------
// WT: bf16 weights in MFMA-frag order [tap][ck][ks][ntile][lane][8]  (unchanged)
#define WT0 0u
#define WT1 1474560u
#define WT2 4423680u
#define WT3 5898240u
#define WT4 6635520u
#define WT5 7372800u
// XA: bf16 A-fragments, zero-padded: [b][C/8][(F+2)^2][8ch] (16B per frag)
#define XA0 8110080u
#define XA1 60538880u
#define XA2 89440256u
#define XA3 94158848u
#define XA4 94961664u
#define XA5 95371264u
// CV: fp32 conv output CONV[s][b][m=y*F+x][n=0..159]
#define CV0 95518720u
#define CV1 125091840u
#define CV2 132485120u
#define CV3 134533120u
#define CV4 135045120u
#define CV5 135229440u
#define WS_TOTAL 135249920u

// ====== prepass 1: OIHW fp32 weights -> bf16 frag order (unchanged) ======
template <int C>
__device__ __forceinline__
void wprep_body(int idx, const float* lw, const float* cw, unsigned short* wt)
{
  if (idx >= 1440 * C) return;
  constexpr int CK = C / 64;
  const int j    = idx & 7;
  const int lane = (idx >> 3) & 63;
  int rest = idx >> 9;
  const int nt  = rest % 5;  rest /= 5;
  const int ks  = rest & 3;  rest >>= 2;
  const int ck  = rest % CK;
  const int tap = rest / CK;
  const int n = nt * 32 + (lane & 31);
  const int c = ck * 64 + ks * 16 + (lane >> 5) * 8 + j;
  float v = 0.f;
  if (n < 24)       v = lw[((size_t)n        * C + c) * 9 + tap];
  else if (n < 150) v = cw[((size_t)(n - 24) * C + c) * 9 + tap];
  __hip_bfloat16 h = __float2bfloat16(v);
  wt[idx] = *(unsigned short*)&h;
}

// ====== prepass 2: NCHW fp32 feats -> padded bf16 A-fragment layout ======
// XA[b][g=c/8][(py)*(F+2)+px][j=0..7], border (py,px==0 or F+1) = 0.
template <int C, int F>
__device__ __forceinline__
void xprep_body(int idx, const float* __restrict__ x, unsigned short* __restrict__ xp)
{
  constexpr int P = F + 2, IMGP = P * P, C8 = C / 8, FF = F * F;
  const int pos = idx % IMGP;
  const int bg  = idx / IMGP;
  const int g   = bg % C8;
  const int b   = bg / C8;
  const int py  = pos / P, px = pos % P;
  uint4 out = {0u, 0u, 0u, 0u};
  if (py >= 1 && py <= F && px >= 1 && px <= F) {
    const float* s = x + (((size_t)(b * C + g * 8) * F + (py - 1)) * F + (px - 1));
    unsigned int u[4];
    #pragma unroll
    for (int k = 0; k < 4; ++k) {
      __hip_bfloat162 h = __float22bfloat162_rn(
          float2{s[(size_t)(2 * k) * FF], s[(size_t)(2 * k + 1) * FF]});
      u[k] = *(unsigned int*)&h;
    }
    out.x = u[0]; out.y = u[1]; out.z = u[2]; out.w = u[3];
  }
  *(uint4*)(xp + (size_t)idx * 8) = out;
}

// block counts (all exact multiples of 256 threads)
#define XB0 12800
#define XB1 7056
#define XB2 1152
#define XB3 196
#define XB4 100
#define XB5 36
#define WB0 2880
#define WB1 5760
#define WB2 2880
#define WB3 1440
#define WB4 1440
#define WB5 1440
#define PB_TOT (XB0+XB1+XB2+XB3+XB4+XB5+WB0+WB1+WB2+WB3+WB4+WB5)

struct PArgs {
  const float* x[6];
  const float* lw[6];
  const float* cw[6];
  unsigned short* xa[6];
  unsigned short* wt[6];
};

__global__ __launch_bounds__(256)
void prep_all(PArgs a)
{
  int blk = blockIdx.x;
  const int t = threadIdx.x;
  if (blk < XB0) { xprep_body<512, 38>(blk * 256 + t, a.x[0], a.xa[0]); return; } blk -= XB0;
  if (blk < XB1) { xprep_body<1024,19>(blk * 256 + t, a.x[1], a.xa[1]); return; } blk -= XB1;
  if (blk < XB2) { xprep_body<512, 10>(blk * 256 + t, a.x[2], a.xa[2]); return; } blk -= XB2;
  if (blk < XB3) { xprep_body<256,  5>(blk * 256 + t, a.x[3], a.xa[3]); return; } blk -= XB3;
  if (blk < XB4) { xprep_body<256,  3>(blk * 256 + t, a.x[4], a.xa[4]); return; } blk -= XB4;
  if (blk < XB5) { xprep_body<256,  1>(blk * 256 + t, a.x[5], a.xa[5]); return; } blk -= XB5;
  if (blk < WB0) { wprep_body<512> (blk * 256 + t, a.lw[0], a.cw[0], a.wt[0]); return; } blk -= WB0;
  if (blk < WB1) { wprep_body<1024>(blk * 256 + t, a.lw[1], a.cw[1], a.wt[1]); return; } blk -= WB1;
  if (blk < WB2) { wprep_body<512> (blk * 256 + t, a.lw[2], a.cw[2], a.wt[2]); return; } blk -= WB2;
  if (blk < WB3) { wprep_body<256> (blk * 256 + t, a.lw[3], a.cw[3], a.wt[3]); return; } blk -= WB3;
  if (blk < WB4) { wprep_body<256> (blk * 256 + t, a.lw[4], a.cw[4], a.wt[4]); return; } blk -= WB4;
                   wprep_body<256> (blk * 256 + t, a.lw[5], a.cw[5], a.wt[5]);
}

// ====== implicit-GEMM conv: 8 waves/block, LDS-staged B, double-buffered ==
// Block = 512 thr = 8 waves: 4 m-sub-waves (64 rows each, m-tile 256) x
// 2 n-groups (nt 0..2 / 3..4). Per (ck,ks) step the block stages the 45 KB
// B-slice [tap][nt][lane][8] into LDS via global_load_lds (16B, linear dest),
// prefetching step+1 while computing step. A-frags from padded XA (L1-hot).
#define BSTEP 2880   // 16B frags per (ck,ks) B-slice: 9 taps * 5 nt * 64 lanes

template <int C, int F>
__device__ __forceinline__
void conv_body(int bid, int tid, const unsigned short* __restrict__ xp,
               const unsigned short* __restrict__ wt, float* __restrict__ cv,
               uint4 (*lB)[BSTEP])
{
  constexpr int FF   = F * F;
  constexpr int MB   = (FF + 255) / 256;
  constexpr int CK   = C / 64;
  constexpr int P    = F + 2;
  constexpr int IMGP = P * P;
  constexpr int C8   = C / 8;
  constexpr int TS   = CK * 10240;   // shorts per tap in WT
  constexpr int NIT  = CK * 4;       // (ck,ks) steps

  const int mt = bid % MB;
  const int b  = bid / MB;

  const int wave = tid >> 6, lane = tid & 63;
  const int mw = wave & 3, ng = wave >> 2;
  const int m0 = mt * 256 + mw * 64;
  const int nbase  = ng * 3;
  const int ncount = ng ? 2 : 3;

  const int cm = lane & 31, khalf = lane >> 5;
  int mi0 = m0 + cm;      if (mi0 > FF - 1) mi0 = FF - 1;
  int mi1 = m0 + 32 + cm; if (mi1 > FF - 1) mi1 = FF - 1;
  const int ay0 = mi0 / F, ax0 = mi0 - ay0 * F;
  const int ay1 = mi1 / F, ax1 = mi1 - ay1 * F;
  const int ylo = m0 / F;                                   // >= F for idle waves -> all taps skip
  const int yhi = ((m0 + 63 < FF - 1) ? (m0 + 63) : (FF - 1)) / F;

  const unsigned short* xb = xp + ((size_t)b * C8 + khalf) * IMGP * 8;
  const int o0 = ((ay0 + 1) * P + ax0 + 1) * 8;
  const int o1 = ((ay1 + 1) * P + ax1 + 1) * 8;

  f32x16 acc[2][3];
  #pragma unroll
  for (int mf = 0; mf < 2; ++mf)
    #pragma unroll
    for (int nt = 0; nt < 3; ++nt)
      #pragma unroll
      for (int r = 0; r < 16; ++r) acc[mf][nt][r] = 0.f;

  // stage B-slice for step 'it' into buf (linear LDS dest, per-lane global src)
  auto stage = [&](uint4* buf, int it) {
    const int ck = it >> 2, ks = it & 3;
    const unsigned short* wck = wt + ck * 10240 + ks * 2560;
    #pragma unroll
    for (int r = 0; r < 6; ++r) {
      const int e = r * 512 + tid;
      if (r < 5 || e < BSTEP) {
        const int tap = e / 320;            // 320 = 5 nt * 64 lanes
        const int w   = e - tap * 320;
        __builtin_amdgcn_global_load_lds(
            (const __attribute__((address_space(1))) unsigned int*)(wck + (size_t)tap * TS + w * 8),
            (__attribute__((address_space(3))) unsigned int*)&buf[e], 16, 0, 0);
      }
    }
  };

  stage(lB[0], 0);
  int cur = 0;
  #pragma unroll 1
  for (int it = 0; it < NIT; ++it) {
    __syncthreads();                          // buf[cur] staged (vmcnt drain)
    if (it + 1 < NIT) stage(lB[cur ^ 1], it + 1);   // prefetch overlaps compute
    const int ck = it >> 2, ks = it & 3;
    const unsigned short* xk = xb + (size_t)(ck * 8 + ks * 2) * IMGP * 8;
    const uint4* bp = lB[cur];
    #pragma unroll
    for (int tap = 0; tap < 9; ++tap) {
      const int dy = tap / 3 - 1, dx = tap % 3 - 1;
      if (ylo + dy >= F || yhi + dy < 0) continue;   // wave-uniform skip
      if (F == 1 && dx != 0) continue;
      const int d = (dy * P + dx) * 8;               // compile-time per tap
      const bf16x8 a0 = *(const bf16x8*)(xk + o0 + d);
      const bf16x8 a1 = *(const bf16x8*)(xk + o1 + d);
      #pragma unroll
      for (int nt = 0; nt < 3; ++nt) {
        if (nt < ncount) {
          const uint4 u = bp[tap * 320 + (nbase + nt) * 64 + lane];
          const bf16x8 bf = *(const bf16x8*)&u;
          acc[0][nt] = __builtin_amdgcn_mfma_f32_32x32x16_bf16(a0, bf, acc[0][nt], 0, 0, 0);
          acc[1][nt] = __builtin_amdgcn_mfma_f32_32x32x16_bf16(a1, bf, acc[1][nt], 0, 0, 0);
        }
      }
    }
    cur ^= 1;
  }

  // plain coalesced stores
  float* cb = cv + (size_t)b * FF * 160;
  #pragma unroll
  for (int mf = 0; mf < 2; ++mf)
    #pragma unroll
    for (int nt = 0; nt < 3; ++nt) {
      if (nt < ncount) {
        const int n = (nbase + nt) * 32 + cm;
        #pragma unroll
        for (int r = 0; r < 16; ++r) {
          const int mm = m0 + mf * 32 + (r & 3) + 8 * (r >> 2) + 4 * khalf;
          if (mm < FF) cb[(size_t)mm * 160 + n] = acc[mf][nt][r];
        }
      }
    }
}

// per-stage block counts: 32 * ceil(FF/256); heaviest (C=1024) first
#define G1B 64
#define G0B 192
#define G2B 32
#define G3B 32
#define G4B 32
#define G5B 32
#define GB_TOT (G1B + G0B + G2B + G3B + G4B + G5B)

__global__ __launch_bounds__(512, 2)
void gemm_all(char* wsb)
{
  __shared__ uint4 lB[2][BSTEP];    // 2 x 45 KB double buffer
  int blk = blockIdx.x;
  const int tid = threadIdx.x;
  if (blk < G1B) { conv_body<1024,19>(blk, tid, (const unsigned short*)(wsb + XA1),
                                      (const unsigned short*)(wsb + WT1), (float*)(wsb + CV1), lB); return; }
  blk -= G1B;
  if (blk < G0B) { conv_body<512, 38>(blk, tid, (const unsigned short*)(wsb + XA0),
                                      (const unsigned short*)(wsb + WT0), (float*)(wsb + CV0), lB); return; }
  blk -= G0B;
  if (blk < G2B) { conv_body<512, 10>(blk, tid, (const unsigned short*)(wsb + XA2),
                                      (const unsigned short*)(wsb + WT2), (float*)(wsb + CV2), lB); return; }
  blk -= G2B;
  if (blk < G3B) { conv_body<256,  5>(blk, tid, (const unsigned short*)(wsb + XA3),
                                      (const unsigned short*)(wsb + WT3), (float*)(wsb + CV3), lB); return; }
  blk -= G3B;
  if (blk < G4B) { conv_body<256,  3>(blk, tid, (const unsigned short*)(wsb + XA4),
                                      (const unsigned short*)(wsb + WT4), (float*)(wsb + CV4), lB); return; }
  blk -= G4B;
                   conv_body<256,  1>(blk, tid, (const unsigned short*)(wsb + XA5),
                                      (const unsigned short*)(wsb + WT5), (float*)(wsb + CV5), lB);
}

// ================= decode: bias + softmax + prior decode ==================
struct DecArgs {
  const float* lb[6];
  const float* cb[6];
};

template <int F>
__device__ __forceinline__
void dec_one(int local, int b, const float* cvs, const float* lb, const float* cb,
             const float* p4, float* o)
{
  constexpr int FF = F * F;
  const int pos = local / 6;
  const int a   = local - pos * 6;
  const float* strip = cvs + ((size_t)b * FF + pos) * 160;

  float cls[21];
  float mx = -1e30f;
  #pragma unroll
  for (int k = 0; k < 21; ++k) {
    cls[k] = strip[24 + a * 21 + k] + cb[a * 21 + k];
    mx = fmaxf(mx, cls[k]);
  }
  float s = 0.f;
  #pragma unroll
  for (int k = 0; k < 21; ++k) { cls[k] = __expf(cls[k] - mx); s += cls[k]; }
  const float inv = 1.f / s;

  const float l0 = strip[a * 4 + 0] + lb[a * 4 + 0];
  const float l1 = strip[a * 4 + 1] + lb[a * 4 + 1];
  const float l2 = strip[a * 4 + 2] + lb[a * 4 + 2];
  const float l3 = strip[a * 4 + 3] + lb[a * 4 + 3];

  const float px = p4[0], py = p4[1], pw = p4[2], ph = p4[3];
  const float cx = px + l0 * 0.1f * pw;
  const float cy = py + l1 * 0.1f * ph;
  const float w  = pw * __expf(l2 * 0.2f);
  const float h  = ph * __expf(l3 * 0.2f);
  const float minx = cx - 0.5f * w;
  const float miny = cy - 0.5f * h;

  o[0] = minx; o[1] = miny; o[2] = minx + w; o[3] = miny + h;
  #pragma unroll
  for (int k = 0; k < 21; ++k) o[4 + k] = cls[k] * inv;
}

__global__ __launch_bounds__(256)
void decode_k(const char* __restrict__ wsb, DecArgs da,
              const float* __restrict__ priors, float* __restrict__ out)
{
  const int gid = blockIdx.x * 256 + threadIdx.x;
  if (gid >= BATCH * NUM_PRIORS) return;
  const int b  = gid / NUM_PRIORS;
  const int pr = gid - b * NUM_PRIORS;
  float* o = out + (size_t)gid * OUT_CH;
  const float* p4 = priors + (size_t)pr * 4;

  if (pr < 8664)       dec_one<38>(pr,         b, (const float*)(wsb + CV0), da.lb[0], da.cb[0], p4, o);
  else if (pr < 10830) dec_one<19>(pr - 8664,  b, (const float*)(wsb + CV1), da.lb[1], da.cb[1], p4, o);
  else if (pr < 11430) dec_one<10>(pr - 10830, b, (const float*)(wsb + CV2), da.lb[2], da.cb[2], p4, o);
  else if (pr < 11580) dec_one<5> (pr - 11430, b, (const float*)(wsb + CV3), da.lb[3], da.cb[3], p4, o);
  else if (pr < 11634) dec_one<3> (pr - 11580, b, (const float*)(wsb + CV4), da.lb[4], da.cb[4], p4, o);
  else                 dec_one<1> (pr - 11634, b, (const float*)(wsb + CV5), da.lb[5], da.cb[5], p4, o);
}

// ================= fallback (round-1 direct kernel, known-good) ===========
#define TH 4
#define TW 8
#define NPOS 32
#define NUM_OC 160
#define WS_STRIDE 161
#define OS 33
#define CC 8

union SmemFB {
  struct {
    float patch[CC * (TH + 2) * (TW + 2)];
    float w[9 * CC * WS_STRIDE];
  } st;
  float outbuf[NUM_OC * OS];
};

template <int C, int F>
__global__ __launch_bounds__(256)
void ssd_stage(const float* __restrict__ x,
               const float* __restrict__ loc_w, const float* __restrict__ loc_b,
               const float* __restrict__ conf_w, const float* __restrict__ conf_b,
               const float* __restrict__ priors,
               float* __restrict__ out, int stage_off)
{
  constexpr int nx = (F + TW - 1) / TW;
  constexpr int ny = (F + TH - 1) / TH;
  __shared__ SmemFB smem;

  const int bid = blockIdx.x;
  const int b   = bid / (nx * ny);
  const int rem = bid % (nx * ny);
  const int ty  = rem / nx;
  const int tx  = rem % nx;
  const int x0  = tx * TW;
  const int y0  = ty * TH;

  const int t = threadIdx.x;
  const int g = t & 31;
  const int p = t >> 5;

  float acc[5][TH] = {};

  #pragma unroll 1
  for (int c0 = 0; c0 < C; c0 += CC) {
    __syncthreads();
    for (int i = t; i < CC * (TH + 2) * (TW + 2); i += 256) {
      int c  = i / ((TH + 2) * (TW + 2));
      int r  = i - c * ((TH + 2) * (TW + 2));
      int yy = r / (TW + 2);
      int xx = r - yy * (TW + 2);
      int gy = y0 + yy - 1;
      int gx = x0 + xx - 1;
      float v = 0.f;
      if (gy >= 0 && gy < F && gx >= 0 && gx < F)
        v = x[(((size_t)b * C + (c0 + c)) * F + gy) * F + gx];
      smem.st.patch[i] = v;
    }
    for (int i = t; i < NUM_OC * (CC * 9); i += 256) {
      int oc  = i / (CC * 9);
      int j   = i - oc * (CC * 9);
      int c   = j / 9;
      int tap = j - c * 9;
      float v = 0.f;
      if (oc < 24)        v = loc_w [((size_t)oc        * C + (c0 + c)) * 9 + tap];
      else if (oc < 150)  v = conf_w[((size_t)(oc - 24) * C + (c0 + c)) * 9 + tap];
      smem.st.w[(tap * CC + c) * WS_STRIDE + oc] = v;
    }
    __syncthreads();

    for (int tap = 0; tap < 9; ++tap) {
      const int ky = tap / 3;
      const int kx = tap - ky * 3;
      const int xbase = ky * (TW + 2) + kx + p;
      const int wbase = tap * CC * WS_STRIDE + g;
      #pragma unroll
      for (int c = 0; c < CC; ++c) {
        float xv[TH];
        #pragma unroll
        for (int v = 0; v < TH; ++v)
          xv[v] = smem.st.patch[c * ((TH + 2) * (TW + 2)) + v * (TW + 2) + xbase];
        #pragma unroll
        for (int u = 0; u < 5; ++u) {
          float wv = smem.st.w[wbase + c * WS_STRIDE + u * 32];
          #pragma unroll
          for (int v = 0; v < TH; ++v)
            acc[u][v] += wv * xv[v];
        }
      }
    }
  }

  __syncthreads();
  #pragma unroll
  for (int u = 0; u < 5; ++u) {
    int oc = g + 32 * u;
    float bias = 0.f;
    if (oc < 24)       bias = loc_b[oc];
    else if (oc < 150) bias = conf_b[oc - 24];
    #pragma unroll
    for (int v = 0; v < TH; ++v)
      smem.outbuf[oc * OS + v * TW + p] = acc[u][v] + bias;
  }
  __syncthreads();

  if (t < NPOS * 6) {
    int pos = t / 6;
    int a   = t - pos * 6;
    int lx  = pos & 7;
    int ly  = pos >> 3;
    int gx  = x0 + lx;
    int gy  = y0 + ly;
    if (gx < F && gy < F) {
      float cls[21];
      float m = -1e30f;
      #pragma unroll
      for (int k = 0; k < 21; ++k) {
        cls[k] = smem.outbuf[(24 + a * 21 + k) * OS + pos];
        m = fmaxf(m, cls[k]);
      }
      float s = 0.f;
      #pragma unroll
      for (int k = 0; k < 21; ++k) { cls[k] = __expf(cls[k] - m); s += cls[k]; }
      float inv = 1.f / s;

      float l0 = smem.outbuf[(a * 4 + 0) * OS + pos];
      float l1 = smem.outbuf[(a * 4 + 1) * OS + pos];
      float l2 = smem.outbuf[(a * 4 + 2) * OS + pos];
      float l3 = smem.outbuf[(a * 4 + 3) * OS + pos];

      int prior = stage_off + (gy * F + gx) * 6 + a;
      const float* pr = priors + (size_t)prior * 4;
      float px = pr[0], py = pr[1], pw = pr[2], ph = pr[3];
      float cx = px + l0 * 0.1f * pw;
      float cy = py + l1 * 0.1f * ph;
      float w  = pw * __expf(l2 * 0.2f);
      float h  = ph * __expf(l3 * 0.2f);
      float minx = cx - 0.5f * w;
      float miny = cy - 0.5f * h;

      float* o = out + ((size_t)b * NUM_PRIORS + prior) * OUT_CH;
      o[0] = minx;
      o[1] = miny;
      o[2] = minx + w;
      o[3] = miny + h;
      #pragma unroll
      for (int k = 0; k < 21; ++k)
        o[4 + k] = cls[k] * inv;
    }
  }
}

template <int C, int F>
static void launch_stage_fb(void* const* d_in, int base, const float* priors, float* out,
                            int stage_off, hipStream_t stream) {
  constexpr int nx = (F + TW - 1) / TW;
  constexpr int ny = (F + TH - 1) / TH;
  int blocks = BATCH * nx * ny;
  ssd_stage<C, F><<<blocks, 256, 0, stream>>>(
      (const float*)d_in[base + 0], (const float*)d_in[base + 1], (const float*)d_in[base + 2],
      (const float*)d_in[base + 3], (const float*)d_in[base + 4], priors, out, stage_off);
}

// ================= launch =================================================
extern "C" void kernel_launch(void* const* d_in, const int* in_sizes, int n_in,
                              void* d_out, int out_size, void* d_ws, size_t ws_size,
                              hipStream_t stream) {
  (void)in_sizes; (void)n_in; (void)out_size;
  const float* priors = (const float*)d_in[30];
  float* out = (float*)d_out;

  if (ws_size < (size_t)WS_TOTAL) {   // deterministic fallback
    launch_stage_fb<512,  38>(d_in,  0, priors, out,     0, stream);
    launch_stage_fb<1024, 19>(d_in,  5, priors, out,  8664, stream);
    launch_stage_fb<512,  10>(d_in, 10, priors, out, 10830, stream);
    launch_stage_fb<256,   5>(d_in, 15, priors, out, 11430, stream);
    launch_stage_fb<256,   3>(d_in, 20, priors, out, 11580, stream);
    launch_stage_fb<256,   1>(d_in, 25, priors, out, 11634, stream);
    return;
  }

  char* wsb = (char*)d_ws;
  static const unsigned wtoff[6] = {WT0, WT1, WT2, WT3, WT4, WT5};
  static const unsigned xaoff[6] = {XA0, XA1, XA2, XA3, XA4, XA5};

  // fused prepass: weights -> frag order, feats -> padded bf16 frags
  PArgs pa;
  for (int s = 0; s < 6; ++s) {
    pa.x[s]  = (const float*)d_in[5 * s];
    pa.lw[s] = (const float*)d_in[5 * s + 1];
    pa.cw[s] = (const float*)d_in[5 * s + 3];
    pa.xa[s] = (unsigned short*)(wsb + xaoff[s]);
    pa.wt[s] = (unsigned short*)(wsb + wtoff[s]);
  }
  prep_all<<<PB_TOT, 256, 0, stream>>>(pa);

  // LDS-staged double-buffered conv (8 waves/block)
  gemm_all<<<GB_TOT, 512, 0, stream>>>(wsb);

  // epilogue: bias + softmax + decode
  DecArgs da;
  for (int s = 0; s < 6; ++s) {
    da.lb[s] = (const float*)d_in[5 * s + 2];
    da.cb[s] = (const float*)d_in[5 * s + 4];
  }
  decode_k<<<(BATCH * NUM_PRIORS + 255) / 256, 256, 0, stream>>>((const char*)d_ws, da, priors, out);
}

// Round 5
// 437.566 us; speedup vs baseline: 1.7350x; 1.1216x over previous
//
#include <hip/hip_runtime.h>
#include <hip/hip_bf16.h>
#include <math.h>

typedef __attribute__((ext_vector_type(8))) short bf16x8;   // 8 bf16 = 4 VGPRs
typedef __attribute__((ext_vector_type(16))) float f32x16;  // 32x32 mfma acc

#define NUM_PRIORS 11640
#define OUT_CH 25
#define BATCH 32

// ---------------- workspace layout (bytes) ----------------
// WT: bf16 weights in MFMA-frag order [tap][ck][ks][ntile][lane][8]  (unchanged)
#define WT0 0u
#define WT1 1474560u
#define WT2 4423680u
#define WT3 5898240u
#define WT4 6635520u
#define WT5 7372800u
// XA: bf16 A-fragments, zero-padded: [b][C/8][(F+2)^2][8ch] (16B per frag)
#define XA0 8110080u
#define XA1 60538880u
#define XA2 89440256u
#define XA3 94158848u
#define XA4 94961664u
#define XA5 95371264u
// CV: fp32 conv output CONV[s][b][m=y*F+x][n=0..159]
#define CV0 95518720u
#define CV1 125091840u
#define CV2 132485120u
#define CV3 134533120u
#define CV4 135045120u
#define CV5 135229440u
#define WS_TOTAL 135249920u

// ====== prepass 1: OIHW fp32 weights -> bf16 frag order (unchanged) ======
template <int C>
__device__ __forceinline__
void wprep_body(int idx, const float* lw, const float* cw, unsigned short* wt)
{
  if (idx >= 1440 * C) return;
  constexpr int CK = C / 64;
  const int j    = idx & 7;
  const int lane = (idx >> 3) & 63;
  int rest = idx >> 9;
  const int nt  = rest % 5;  rest /= 5;
  const int ks  = rest & 3;  rest >>= 2;
  const int ck  = rest % CK;
  const int tap = rest / CK;
  const int n = nt * 32 + (lane & 31);
  const int c = ck * 64 + ks * 16 + (lane >> 5) * 8 + j;
  float v = 0.f;
  if (n < 24)       v = lw[((size_t)n        * C + c) * 9 + tap];
  else if (n < 150) v = cw[((size_t)(n - 24) * C + c) * 9 + tap];
  __hip_bfloat16 h = __float2bfloat16(v);
  wt[idx] = *(unsigned short*)&h;
}

// ====== prepass 2: NCHW fp32 feats -> padded bf16 A-fragment layout ======
// XA[b][g=c/8][(py)*(F+2)+px][j=0..7], border (py,px==0 or F+1) = 0.
template <int C, int F>
__device__ __forceinline__
void xprep_body(int idx, const float* __restrict__ x, unsigned short* __restrict__ xp)
{
  constexpr int P = F + 2, IMGP = P * P, C8 = C / 8, FF = F * F;
  const int pos = idx % IMGP;
  const int bg  = idx / IMGP;
  const int g   = bg % C8;
  const int b   = bg / C8;
  const int py  = pos / P, px = pos % P;
  uint4 out = {0u, 0u, 0u, 0u};
  if (py >= 1 && py <= F && px >= 1 && px <= F) {
    const float* s = x + (((size_t)(b * C + g * 8) * F + (py - 1)) * F + (px - 1));
    unsigned int u[4];
    #pragma unroll
    for (int k = 0; k < 4; ++k) {
      __hip_bfloat162 h = __float22bfloat162_rn(
          float2{s[(size_t)(2 * k) * FF], s[(size_t)(2 * k + 1) * FF]});
      u[k] = *(unsigned int*)&h;
    }
    out.x = u[0]; out.y = u[1]; out.z = u[2]; out.w = u[3];
  }
  *(uint4*)(xp + (size_t)idx * 8) = out;
}

// block counts (all exact multiples of 256 threads)
#define XB0 12800
#define XB1 7056
#define XB2 1152
#define XB3 196
#define XB4 100
#define XB5 36
#define WB0 2880
#define WB1 5760
#define WB2 2880
#define WB3 1440
#define WB4 1440
#define WB5 1440
#define PB_TOT (XB0+XB1+XB2+XB3+XB4+XB5+WB0+WB1+WB2+WB3+WB4+WB5)

struct PArgs {
  const float* x[6];
  const float* lw[6];
  const float* cw[6];
  unsigned short* xa[6];
  unsigned short* wt[6];
};

__global__ __launch_bounds__(256)
void prep_all(PArgs a)
{
  int blk = blockIdx.x;
  const int t = threadIdx.x;
  if (blk < XB0) { xprep_body<512, 38>(blk * 256 + t, a.x[0], a.xa[0]); return; } blk -= XB0;
  if (blk < XB1) { xprep_body<1024,19>(blk * 256 + t, a.x[1], a.xa[1]); return; } blk -= XB1;
  if (blk < XB2) { xprep_body<512, 10>(blk * 256 + t, a.x[2], a.xa[2]); return; } blk -= XB2;
  if (blk < XB3) { xprep_body<256,  5>(blk * 256 + t, a.x[3], a.xa[3]); return; } blk -= XB3;
  if (blk < XB4) { xprep_body<256,  3>(blk * 256 + t, a.x[4], a.xa[4]); return; } blk -= XB4;
  if (blk < XB5) { xprep_body<256,  1>(blk * 256 + t, a.x[5], a.xa[5]); return; } blk -= XB5;
  if (blk < WB0) { wprep_body<512> (blk * 256 + t, a.lw[0], a.cw[0], a.wt[0]); return; } blk -= WB0;
  if (blk < WB1) { wprep_body<1024>(blk * 256 + t, a.lw[1], a.cw[1], a.wt[1]); return; } blk -= WB1;
  if (blk < WB2) { wprep_body<512> (blk * 256 + t, a.lw[2], a.cw[2], a.wt[2]); return; } blk -= WB2;
  if (blk < WB3) { wprep_body<256> (blk * 256 + t, a.lw[3], a.cw[3], a.wt[3]); return; } blk -= WB3;
  if (blk < WB4) { wprep_body<256> (blk * 256 + t, a.lw[4], a.cw[4], a.wt[4]); return; } blk -= WB4;
                   wprep_body<256> (blk * 256 + t, a.lw[5], a.cw[5], a.wt[5]);
}

// ====== implicit-GEMM conv: VMEM-free compute, A+B LDS double-buffered ====
// Block = 512 thr = 8 waves: 4 m-sub-waves (64 rows, m-tile 256) x 2 n-groups
// (nt 0..2 / 3..4). Per (ck,ks) step the block stages the 45 KB B-slice AND
// the <=12.8 KB A-window into LDS via global_load_lds (uniform exec, linear
// dest, clamped src). Compute phase has ZERO global loads, so the single
// __syncthreads drain per step waits only on staging issued one full compute
// phase earlier (true double-buffer overlap; no in-order vmcnt forcing).
#define BSTEP 2880    // real B frags per (ck,ks): 9 taps * 5 nt * 64 lanes
#define BPAD  3072    // padded to 6 full 512-thread rounds
#define APAD  1024    // padded A frags (2 full rounds); real = 2*AR*(F+2)

template <int C, int F>
__device__ __forceinline__
void conv_body(int bid, int tid, const unsigned short* __restrict__ xp,
               const unsigned short* __restrict__ wt, float* __restrict__ cv,
               uint4 (*lB)[BPAD], uint4 (*lA)[APAD])
{
  constexpr int FF   = F * F;
  constexpr int MB   = (FF + 255) / 256;
  constexpr int CK   = C / 64;
  constexpr int P    = F + 2;
  constexpr int IMGP = P * P;
  constexpr int C8   = C / 8;
  constexpr int TS   = CK * 10240;   // shorts per tap in WT
  constexpr int NIT  = CK * 4;       // (ck,ks) steps
  constexpr int AR   = ((255 / F + 4) < P) ? (255 / F + 4) : P;  // A-window rows
  constexpr int ANP  = AR * P;       // frags per plane

  const int mt = bid % MB;
  const int b  = bid / MB;

  const int wave = tid >> 6, lane = tid & 63;
  const int mw = wave & 3, ng = wave >> 2;
  const int m0 = mt * 256 + mw * 64;
  const int nbase  = ng * 3;
  const int ncount = ng ? 2 : 3;

  const int cm = lane & 31, khalf = lane >> 5;
  int mi0 = m0 + cm;      if (mi0 > FF - 1) mi0 = FF - 1;
  int mi1 = m0 + 32 + cm; if (mi1 > FF - 1) mi1 = FF - 1;
  const int ay0 = mi0 / F, ax0 = mi0 - ay0 * F;
  const int ay1 = mi1 / F, ax1 = mi1 - ay1 * F;
  const int ylo = m0 / F;                                   // per-wave (tap skip)
  const int yhi = ((m0 + 63 < FF - 1) ? (m0 + 63) : (FF - 1)) / F;

  // block-uniform A window start (padded coords)
  const int bylo = (mt * 256) / F;
  const int wy0  = (bylo < P - AR) ? bylo : (P - AR);

  // lane A frag offsets inside LDS window
  const int af0 = (khalf * AR + (ay0 + 1 - wy0)) * P + (ax0 + 1);
  const int af1 = (khalf * AR + (ay1 + 1 - wy0)) * P + (ax1 + 1);

  f32x16 acc[2][3];
  #pragma unroll
  for (int mf = 0; mf < 2; ++mf)
    #pragma unroll
    for (int nt = 0; nt < 3; ++nt)
      #pragma unroll
      for (int r = 0; r < 16; ++r) acc[mf][nt][r] = 0.f;

  // stage A+B slices for step 'it2' (uniform exec: sources clamped, dest pad)
  auto stage = [&](int buf, int it2) {
    const int ck = it2 >> 2, ks = it2 & 3;
    const unsigned short* wck = wt + ck * 10240 + ks * 2560;
    #pragma unroll
    for (int r = 0; r < 6; ++r) {
      const int e  = r * 512 + tid;
      const int es = (e < BSTEP) ? e : (BSTEP - 1);
      const int tap = es / 320;            // 320 = 5 nt * 64 lanes
      const int w   = es - tap * 320;
      __builtin_amdgcn_global_load_lds(
          (const __attribute__((address_space(1))) unsigned int*)(wck + (size_t)tap * TS + w * 8),
          (__attribute__((address_space(3))) unsigned int*)&lB[buf][e], 16, 0, 0);
    }
    const unsigned short* xbb = xp + ((size_t)b * C8 + ck * 8 + ks * 2) * IMGP * 8;
    #pragma unroll
    for (int r = 0; r < 2; ++r) {
      const int e  = r * 512 + tid;
      const int es = (e < 2 * ANP) ? e : (2 * ANP - 1);
      const int p  = es / ANP;
      const int rr = es - p * ANP;
      const int ar = rr / P, ac = rr - ar * P;
      __builtin_amdgcn_global_load_lds(
          (const __attribute__((address_space(1))) unsigned int*)
              (xbb + ((size_t)p * IMGP + (wy0 + ar) * P + ac) * 8),
          (__attribute__((address_space(3))) unsigned int*)&lA[buf][e], 16, 0, 0);
    }
  };

  stage(0, 0);
  #pragma unroll 1
  for (int it = 0; it < NIT; ++it) {
    __syncthreads();     // drains vmcnt: stage(it) complete; prior reads done
    if (it + 1 < NIT) stage((it + 1) & 1, it + 1);   // overlaps compute below
    const uint4* ap = lA[it & 1];
    const uint4* bp = lB[it & 1];
    __builtin_amdgcn_s_setprio(1);
    #pragma unroll
    for (int tap = 0; tap < 9; ++tap) {
      const int dy = tap / 3 - 1, dx = tap % 3 - 1;
      if (ylo + dy >= F || yhi + dy < 0) continue;   // wave-uniform skip
      if (F == 1 && dx != 0) continue;
      const int d = dy * P + dx;                     // compile-time per tap
      const uint4 ua0 = ap[af0 + d];
      const uint4 ua1 = ap[af1 + d];
      const bf16x8 a0 = *(const bf16x8*)&ua0;
      const bf16x8 a1 = *(const bf16x8*)&ua1;
      #pragma unroll
      for (int nt = 0; nt < 3; ++nt) {
        if (nt < ncount) {
          const uint4 u = bp[tap * 320 + (nbase + nt) * 64 + lane];
          const bf16x8 bf = *(const bf16x8*)&u;
          acc[0][nt] = __builtin_amdgcn_mfma_f32_32x32x16_bf16(a0, bf, acc[0][nt], 0, 0, 0);
          acc[1][nt] = __builtin_amdgcn_mfma_f32_32x32x16_bf16(a1, bf, acc[1][nt], 0, 0, 0);
        }
      }
    }
    __builtin_amdgcn_s_setprio(0);
  }

  // plain coalesced stores
  float* cb = cv + (size_t)b * FF * 160;
  #pragma unroll
  for (int mf = 0; mf < 2; ++mf)
    #pragma unroll
    for (int nt = 0; nt < 3; ++nt) {
      if (nt < ncount) {
        const int n = (nbase + nt) * 32 + cm;
        #pragma unroll
        for (int r = 0; r < 16; ++r) {
          const int mm = m0 + mf * 32 + (r & 3) + 8 * (r >> 2) + 4 * khalf;
          if (mm < FF) cb[(size_t)mm * 160 + n] = acc[mf][nt][r];
        }
      }
    }
}

// per-stage block counts: 32 * ceil(FF/256); heaviest (C=1024) first
#define G1B 64
#define G0B 192
#define G2B 32
#define G3B 32
#define G4B 32
#define G5B 32
#define GB_TOT (G1B + G0B + G2B + G3B + G4B + G5B)

__global__ __launch_bounds__(512, 2)
void gemm_all(char* wsb)
{
  __shared__ uint4 lB[2][BPAD];   // 96 KB
  __shared__ uint4 lA[2][APAD];   // 32 KB
  int blk = blockIdx.x;
  const int tid = threadIdx.x;
  if (blk < G1B) { conv_body<1024,19>(blk, tid, (const unsigned short*)(wsb + XA1),
                                      (const unsigned short*)(wsb + WT1), (float*)(wsb + CV1), lB, lA); return; }
  blk -= G1B;
  if (blk < G0B) { conv_body<512, 38>(blk, tid, (const unsigned short*)(wsb + XA0),
                                      (const unsigned short*)(wsb + WT0), (float*)(wsb + CV0), lB, lA); return; }
  blk -= G0B;
  if (blk < G2B) { conv_body<512, 10>(blk, tid, (const unsigned short*)(wsb + XA2),
                                      (const unsigned short*)(wsb + WT2), (float*)(wsb + CV2), lB, lA); return; }
  blk -= G2B;
  if (blk < G3B) { conv_body<256,  5>(blk, tid, (const unsigned short*)(wsb + XA3),
                                      (const unsigned short*)(wsb + WT3), (float*)(wsb + CV3), lB, lA); return; }
  blk -= G3B;
  if (blk < G4B) { conv_body<256,  3>(blk, tid, (const unsigned short*)(wsb + XA4),
                                      (const unsigned short*)(wsb + WT4), (float*)(wsb + CV4), lB, lA); return; }
  blk -= G4B;
                   conv_body<256,  1>(blk, tid, (const unsigned short*)(wsb + XA5),
                                      (const unsigned short*)(wsb + WT5), (float*)(wsb + CV5), lB, lA);
}

// ================= decode: bias + softmax + prior decode ==================
struct DecArgs {
  const float* lb[6];
  const float* cb[6];
};

template <int F>
__device__ __forceinline__
void dec_one(int local, int b, const float* cvs, const float* lb, const float* cb,
             const float* p4, float* o)
{
  constexpr int FF = F * F;
  const int pos = local / 6;
  const int a   = local - pos * 6;
  const float* strip = cvs + ((size_t)b * FF + pos) * 160;

  float cls[21];
  float mx = -1e30f;
  #pragma unroll
  for (int k = 0; k < 21; ++k) {
    cls[k] = strip[24 + a * 21 + k] + cb[a * 21 + k];
    mx = fmaxf(mx, cls[k]);
  }
  float s = 0.f;
  #pragma unroll
  for (int k = 0; k < 21; ++k) { cls[k] = __expf(cls[k] - mx); s += cls[k]; }
  const float inv = 1.f / s;

  const float l0 = strip[a * 4 + 0] + lb[a * 4 + 0];
  const float l1 = strip[a * 4 + 1] + lb[a * 4 + 1];
  const float l2 = strip[a * 4 + 2] + lb[a * 4 + 2];
  const float l3 = strip[a * 4 + 3] + lb[a * 4 + 3];

  const float px = p4[0], py = p4[1], pw = p4[2], ph = p4[3];
  const float cx = px + l0 * 0.1f * pw;
  const float cy = py + l1 * 0.1f * ph;
  const float w  = pw * __expf(l2 * 0.2f);
  const float h  = ph * __expf(l3 * 0.2f);
  const float minx = cx - 0.5f * w;
  const float miny = cy - 0.5f * h;

  o[0] = minx; o[1] = miny; o[2] = minx + w; o[3] = miny + h;
  #pragma unroll
  for (int k = 0; k < 21; ++k) o[4 + k] = cls[k] * inv;
}

__global__ __launch_bounds__(256)
void decode_k(const char* __restrict__ wsb, DecArgs da,
              const float* __restrict__ priors, float* __restrict__ out)
{
  const int gid = blockIdx.x * 256 + threadIdx.x;
  if (gid >= BATCH * NUM_PRIORS) return;
  const int b  = gid / NUM_PRIORS;
  const int pr = gid - b * NUM_PRIORS;
  float* o = out + (size_t)gid * OUT_CH;
  const float* p4 = priors + (size_t)pr * 4;

  if (pr < 8664)       dec_one<38>(pr,         b, (const float*)(wsb + CV0), da.lb[0], da.cb[0], p4, o);
  else if (pr < 10830) dec_one<19>(pr - 8664,  b, (const float*)(wsb + CV1), da.lb[1], da.cb[1], p4, o);
  else if (pr < 11430) dec_one<10>(pr - 10830, b, (const float*)(wsb + CV2), da.lb[2], da.cb[2], p4, o);
  else if (pr < 11580) dec_one<5> (pr - 11430, b, (const float*)(wsb + CV3), da.lb[3], da.cb[3], p4, o);
  else if (pr < 11634) dec_one<3> (pr - 11580, b, (const float*)(wsb + CV4), da.lb[4], da.cb[4], p4, o);
  else                 dec_one<1> (pr - 11634, b, (const float*)(wsb + CV5), da.lb[5], da.cb[5], p4, o);
}

// ================= fallback (round-1 direct kernel, known-good) ===========
#define TH 4
#define TW 8
#define NPOS 32
#define NUM_OC 160
#define WS_STRIDE 161
#define OS 33
#define CC 8

union SmemFB {
  struct {
    float patch[CC * (TH + 2) * (TW + 2)];
    float w[9 * CC * WS_STRIDE];
  } st;
  float outbuf[NUM_OC * OS];
};

template <int C, int F>
__global__ __launch_bounds__(256)
void ssd_stage(const float* __restrict__ x,
               const float* __restrict__ loc_w, const float* __restrict__ loc_b,
               const float* __restrict__ conf_w, const float* __restrict__ conf_b,
               const float* __restrict__ priors,
               float* __restrict__ out, int stage_off)
{
  constexpr int nx = (F + TW - 1) / TW;
  constexpr int ny = (F + TH - 1) / TH;
  __shared__ SmemFB smem;

  const int bid = blockIdx.x;
  const int b   = bid / (nx * ny);
  const int rem = bid % (nx * ny);
  const int ty  = rem / nx;
  const int tx  = rem % nx;
  const int x0  = tx * TW;
  const int y0  = ty * TH;

  const int t = threadIdx.x;
  const int g = t & 31;
  const int p = t >> 5;

  float acc[5][TH] = {};

  #pragma unroll 1
  for (int c0 = 0; c0 < C; c0 += CC) {
    __syncthreads();
    for (int i = t; i < CC * (TH + 2) * (TW + 2); i += 256) {
      int c  = i / ((TH + 2) * (TW + 2));
      int r  = i - c * ((TH + 2) * (TW + 2));
      int yy = r / (TW + 2);
      int xx = r - yy * (TW + 2);
      int gy = y0 + yy - 1;
      int gx = x0 + xx - 1;
      float v = 0.f;
      if (gy >= 0 && gy < F && gx >= 0 && gx < F)
        v = x[(((size_t)b * C + (c0 + c)) * F + gy) * F + gx];
      smem.st.patch[i] = v;
    }
    for (int i = t; i < NUM_OC * (CC * 9); i += 256) {
      int oc  = i / (CC * 9);
      int j   = i - oc * (CC * 9);
      int c   = j / 9;
      int tap = j - c * 9;
      float v = 0.f;
      if (oc < 24)        v = loc_w [((size_t)oc        * C + (c0 + c)) * 9 + tap];
      else if (oc < 150)  v = conf_w[((size_t)(oc - 24) * C + (c0 + c)) * 9 + tap];
      smem.st.w[(tap * CC + c) * WS_STRIDE + oc] = v;
    }
    __syncthreads();

    for (int tap = 0; tap < 9; ++tap) {
      const int ky = tap / 3;
      const int kx = tap - ky * 3;
      const int xbase = ky * (TW + 2) + kx + p;
      const int wbase = tap * CC * WS_STRIDE + g;
      #pragma unroll
      for (int c = 0; c < CC; ++c) {
        float xv[TH];
        #pragma unroll
        for (int v = 0; v < TH; ++v)
          xv[v] = smem.st.patch[c * ((TH + 2) * (TW + 2)) + v * (TW + 2) + xbase];
        #pragma unroll
        for (int u = 0; u < 5; ++u) {
          float wv = smem.st.w[wbase + c * WS_STRIDE + u * 32];
          #pragma unroll
          for (int v = 0; v < TH; ++v)
            acc[u][v] += wv * xv[v];
        }
      }
    }
  }

  __syncthreads();
  #pragma unroll
  for (int u = 0; u < 5; ++u) {
    int oc = g + 32 * u;
    float bias = 0.f;
    if (oc < 24)       bias = loc_b[oc];
    else if (oc < 150) bias = conf_b[oc - 24];
    #pragma unroll
    for (int v = 0; v < TH; ++v)
      smem.outbuf[oc * OS + v * TW + p] = acc[u][v] + bias;
  }
  __syncthreads();

  if (t < NPOS * 6) {
    int pos = t / 6;
    int a   = t - pos * 6;
    int lx  = pos & 7;
    int ly  = pos >> 3;
    int gx  = x0 + lx;
    int gy  = y0 + ly;
    if (gx < F && gy < F) {
      float cls[21];
      float m = -1e30f;
      #pragma unroll
      for (int k = 0; k < 21; ++k) {
        cls[k] = smem.outbuf[(24 + a * 21 + k) * OS + pos];
        m = fmaxf(m, cls[k]);
      }
      float s = 0.f;
      #pragma unroll
      for (int k = 0; k < 21; ++k) { cls[k] = __expf(cls[k] - m); s += cls[k]; }
      float inv = 1.f / s;

      float l0 = smem.outbuf[(a * 4 + 0) * OS + pos];
      float l1 = smem.outbuf[(a * 4 + 1) * OS + pos];
      float l2 = smem.outbuf[(a * 4 + 2) * OS + pos];
      float l3 = smem.outbuf[(a * 4 + 3) * OS + pos];

      int prior = stage_off + (gy * F + gx) * 6 + a;
      const float* pr = priors + (size_t)prior * 4;
      float px = pr[0], py = pr[1], pw = pr[2], ph = pr[3];
      float cx = px + l0 * 0.1f * pw;
      float cy = py + l1 * 0.1f * ph;
      float w  = pw * __expf(l2 * 0.2f);
      float h  = ph * __expf(l3 * 0.2f);
      float minx = cx - 0.5f * w;
      float miny = cy - 0.5f * h;

      float* o = out + ((size_t)b * NUM_PRIORS + prior) * OUT_CH;
      o[0] = minx;
      o[1] = miny;
      o[2] = minx + w;
      o[3] = miny + h;
      #pragma unroll
      for (int k = 0; k < 21; ++k)
        o[4 + k] = cls[k] * inv;
    }
  }
}

template <int C, int F>
static void launch_stage_fb(void* const* d_in, int base, const float* priors, float* out,
                            int stage_off, hipStream_t stream) {
  constexpr int nx = (F + TW - 1) / TW;
  constexpr int ny = (F + TH - 1) / TH;
  int blocks = BATCH * nx * ny;
  ssd_stage<C, F><<<blocks, 256, 0, stream>>>(
      (const float*)d_in[base + 0], (const float*)d_in[base + 1], (const float*)d_in[base + 2],
      (const float*)d_in[base + 3], (const float*)d_in[base + 4], priors, out, stage_off);
}

// ================= launch =================================================
extern "C" void kernel_launch(void* const* d_in, const int* in_sizes, int n_in,
                              void* d_out, int out_size, void* d_ws, size_t ws_size,
                              hipStream_t stream) {
  (void)in_sizes; (void)n_in; (void)out_size;
  const float* priors = (const float*)d_in[30];
  float* out = (float*)d_out;

  if (ws_size < (size_t)WS_TOTAL) {   // deterministic fallback
    launch_stage_fb<512,  38>(d_in,  0, priors, out,     0, stream);
    launch_stage_fb<1024, 19>(d_in,  5, priors, out,  8664, stream);
    launch_stage_fb<512,  10>(d_in, 10, priors, out, 10830, stream);
    launch_stage_fb<256,   5>(d_in, 15, priors, out, 11430, stream);
    launch_stage_fb<256,   3>(d_in, 20, priors, out, 11580, stream);
    launch_stage_fb<256,   1>(d_in, 25, priors, out, 11634, stream);
    return;
  }

  char* wsb = (char*)d_ws;
  static const unsigned wtoff[6] = {WT0, WT1, WT2, WT3, WT4, WT5};
  static const unsigned xaoff[6] = {XA0, XA1, XA2, XA3, XA4, XA5};

  // fused prepass: weights -> frag order, feats -> padded bf16 frags
  PArgs pa;
  for (int s = 0; s < 6; ++s) {
    pa.x[s]  = (const float*)d_in[5 * s];
    pa.lw[s] = (const float*)d_in[5 * s + 1];
    pa.cw[s] = (const float*)d_in[5 * s + 3];
    pa.xa[s] = (unsigned short*)(wsb + xaoff[s]);
    pa.wt[s] = (unsigned short*)(wsb + wtoff[s]);
  }
  prep_all<<<PB_TOT, 256, 0, stream>>>(pa);

  // VMEM-free-compute conv (A+B LDS double-buffered, 8 waves/block)
  gemm_all<<<GB_TOT, 512, 0, stream>>>(wsb);

  // epilogue: bias + softmax + decode
  DecArgs da;
  for (int s = 0; s < 6; ++s) {
    da.lb[s] = (const float*)d_in[5 * s + 2];
    da.cb[s] = (const float*)d_in[5 * s + 4];
  }
  decode_k<<<(BATCH * NUM_PRIORS + 255) / 256, 256, 0, stream>>>((const char*)d_ws, da, priors, out);
}